// Round 11
// baseline (311.122 us; speedup 1.0000x reference)
//
#include <hip/hip_runtime.h>
#include <stdint.h>
#include <stddef.h>

#define NN 8192
#define DD 256
#define HH 128

typedef short bf16x8  __attribute__((ext_vector_type(8)));
typedef float f32x4   __attribute__((ext_vector_type(4)));
typedef float f32x16  __attribute__((ext_vector_type(16)));
typedef int   i32x4   __attribute__((ext_vector_type(4)));

// f32 -> bf16 RNE
static __device__ __forceinline__ short f2bf(float x){
  unsigned u = __float_as_uint(x);
  u = (u + 0x7FFFu + ((u >> 16) & 1u)) >> 16;
  return (short)(unsigned short)u;
}
static __device__ __forceinline__ bf16x8 cvt8(const float* p){
  f32x4 a = *(const f32x4*)p;
  f32x4 b = *(const f32x4*)(p + 4);
  bf16x8 o;
  o[0]=f2bf(a[0]); o[1]=f2bf(a[1]); o[2]=f2bf(a[2]); o[3]=f2bf(a[3]);
  o[4]=f2bf(b[0]); o[5]=f2bf(b[1]); o[6]=f2bf(b[2]); o[7]=f2bf(b[3]);
  return o;
}
static __device__ __forceinline__ bf16x8 ld16(const void* p){
  i32x4 v = *(const i32x4*)p;
  return __builtin_bit_cast(bf16x8, v);
}

// ---------- k_prep: ftfrag (all blocks) + projections (blocks 0-127) ----------
// (R7-verified, unchanged)
__global__ __launch_bounds__(256) void k_prep(const float* __restrict__ f,
                                              const float* __restrict__ Wq,
                                              const float* __restrict__ Wk,
                                              unsigned short* __restrict__ ftf,
                                              unsigned short* __restrict__ Qnf,
                                              unsigned short* __restrict__ Kn){
  __shared__ unsigned short wb[128][40];
  int t = threadIdx.x, l = t & 63;
  {
    int fr = blockIdx.x * 4 + (t >> 6);
    int jt = fr >> 3, dt = fr & 7;
    int j = jt * 16 + (l >> 5) * 8, d = dt * 32 + (l & 31);
    bf16x8 o;
    #pragma unroll
    for (int e = 0; e < 8; ++e) o[e] = f2bf(f[(size_t)(j + e) * DD + d]);
    *(bf16x8*)(ftf + (size_t)fr * 512 + l * 8) = o;
  }
  if (blockIdx.x >= 128) return;
  int wave = t >> 6;
  int i0 = blockIdx.x * 64 + wave * 16;
  int lr = l & 15, lk = l >> 4;
  bf16x8 ka[8];
  #pragma unroll
  for (int ks = 0; ks < 8; ++ks)
    ka[ks] = cvt8(f + (size_t)(i0 + lr) * DD + ks * 32 + lk * 8);
  for (int pj = 0; pj < 2; ++pj){
    const float* W = pj ? Wk : Wq;
    f32x4 acc[8];
    #pragma unroll
    for (int n = 0; n < 8; ++n) acc[n] = (f32x4){0.f,0.f,0.f,0.f};
    for (int ks = 0; ks < 8; ++ks){
      __syncthreads();
      { int row = t >> 1, c0 = (t & 1) * 16;
        const float* wp = W + (size_t)row * DD + ks * 32 + c0;
        bf16x8 w0 = cvt8(wp), w1 = cvt8(wp + 8);
        *(bf16x8*)&wb[row][c0]     = w0;
        *(bf16x8*)&wb[row][c0 + 8] = w1; }
      __syncthreads();
      #pragma unroll
      for (int n = 0; n < 8; ++n){
        bf16x8 bb = ld16(&wb[n * 16 + lr][lk * 8]);
        acc[n] = __builtin_amdgcn_mfma_f32_16x16x32_bf16(ka[ks], bb, acc[n], 0, 0, 0);
      }
    }
    #pragma unroll
    for (int r = 0; r < 4; ++r){
      float n2 = 0.f;
      #pragma unroll
      for (int n = 0; n < 8; ++n){ float v = acc[n][r]; n2 += v * v; }
      n2 += __shfl_xor(n2, 1); n2 += __shfl_xor(n2, 2);
      n2 += __shfl_xor(n2, 4); n2 += __shfl_xor(n2, 8);
      float s = 1.f / fmaxf(sqrtf(n2), 1e-4f);   // torch cosine eps
      int row = i0 + lk * 4 + r;
      #pragma unroll
      for (int n = 0; n < 8; ++n){
        short v = f2bf(acc[n][r] * s);
        if (pj){
          Kn[(size_t)row * HH + n * 16 + lr] = (unsigned short)v;
        } else {
          size_t off = ((size_t)(row >> 5) * 8 + n) * 512
                     + ((row & 31) + 32 * (lr >> 3)) * 8 + (lr & 7);
          Qnf[off] = (unsigned short)v;
        }
      }
    }
  }
}

// ---------- fused attention v11: BM=32, 128-j steps, 3 blocks/CU ----------
// 1024 blocks = 256 ib x 4 js. 4 waves: wave w = QK j-sub w AND PV d-quarter w.
// Per 128-j step: adj 32x128 tile dbuf in LDS (coalesced), QK (8 mfma) ->
// exp via LDS mask -> P[32][128] via swizzled LDS -> PV (16 mfma).
// Small acc (32 VGPR) + LDS-resident Kn => fits 3 blocks/CU (12 waves/CU).
__global__ __launch_bounds__(256, 3) void k_attn(
      const int* __restrict__ adj,
      const unsigned short* __restrict__ Qnf, const unsigned short* __restrict__ Kn,
      const unsigned short* __restrict__ ftf,
      float* __restrict__ num_p, float* __restrict__ den_p){
  __shared__ __attribute__((aligned(16))) char p_lds[8192];    // P [32i][128j] bf16 swizzled
  __shared__ __attribute__((aligned(16))) char kn_lds[8192];   // Kn [32i][128h] bf16 swizzled
  __shared__ __attribute__((aligned(16))) int adj_s[2][32][128]; // adj tiles, dbuf (32KB)
  int t = threadIdx.x, w = t >> 6, l = t & 63;
  int lc = l & 31, h = l >> 5;
  int ib = blockIdx.x >> 2, js = blockIdx.x & 3;   // bid%8 -> fixed js per XCD
  int i0 = ib * 32;
  int jbase = js * 2048;
  int kswz = (lc & 7) << 4;
  int arow = t >> 3;              // 32 rows, 8 thr/row
  int acold = (t & 7) * 16;       // dword start; each thr 64B contiguous

  // stage Kn[i0..i0+31][0..127] -> swizzled LDS
  { int row = t >> 3, c = t & 7;  // 8 thr/row, 32B each
    const unsigned short* kp = Kn + (size_t)(i0 + row) * HH + c * 16;
    #pragma unroll
    for (int q = 0; q < 2; ++q){
      i32x4 v = *(const i32x4*)(kp + q * 8);
      *(i32x4*)(kn_lds + row * 256 + ((c * 32 + q * 16) ^ ((row & 7) << 4))) = v;
    } }
  // stage adj(0)
  #pragma unroll
  for (int q = 0; q < 4; ++q){
    i32x4 v = __builtin_nontemporal_load(
        (const i32x4*)(adj + (size_t)(i0 + arow) * NN + jbase + acold + q * 4));
    *(i32x4*)&adj_s[0][arow][acold + q * 4] = v;
  }
  __syncthreads();

  f32x16 pv0, pv1;
  #pragma unroll
  for (int e = 0; e < 16; ++e){ pv0[e] = 0.f; pv1[e] = 0.f; }
  float dacc[16];
  #pragma unroll
  for (int r = 0; r < 16; ++r) dacc[r] = 0.f;

  for (int s = 0; s < 16; ++s){
    int j0 = jbase + s * 128;
    int cur = s & 1, nxt = cur ^ 1;

    // adj(s+1) prefetch (regs, coalesced 64B/thread)
    i32x4 av0, av1, av2, av3;
    if (s < 15){
      const int* ap = adj + (size_t)(i0 + arow) * NN + j0 + 128 + acold;
      av0 = __builtin_nontemporal_load((const i32x4*)(ap));
      av1 = __builtin_nontemporal_load((const i32x4*)(ap + 4));
      av2 = __builtin_nontemporal_load((const i32x4*)(ap + 8));
      av3 = __builtin_nontemporal_load((const i32x4*)(ap + 12));
    }

    // Qn B-frags for this wave's j-sub (L2)
    bf16x8 qv[8];
    { const unsigned short* qb = Qnf + ((size_t)((j0 + w * 32) >> 5) * 8) * 512 + (size_t)l * 8;
      #pragma unroll
      for (int hs = 0; hs < 8; ++hs) qv[hs] = ld16(qb + hs * 512); }

    // QK^T: st[r] = S[i0 + (r&3)+8*(r>>2)+4h][j0 + w*32 + lc]
    f32x16 st;
    #pragma unroll
    for (int e = 0; e < 16; ++e) st[e] = 0.f;
    #pragma unroll
    for (int hs = 0; hs < 8; ++hs){
      bf16x8 kb = ld16(kn_lds + lc * 256 + ((hs * 32 + h * 16) ^ kswz));
      st = __builtin_amdgcn_mfma_f32_32x32x16_bf16(kb, qv[hs], st, 0, 0, 0);
    }

    // ft B-frags first half (kk 0..3), issued early for PV
    bf16x8 bvA[8];
    #pragma unroll
    for (int kk = 0; kk < 4; ++kk){
      const unsigned short* fb = ftf + ((size_t)((j0 + kk * 16) >> 4) * 8 + w * 2) * 512 + (size_t)l * 8;
      bvA[kk * 2]     = ld16(fb);
      bvA[kk * 2 + 1] = ld16(fb + 512);
    }

    // mask -> exp -> P to swizzled LDS
    #pragma unroll
    for (int r = 0; r < 16; ++r){
      int row = (r & 3) + 8 * (r >> 2) + 4 * h;
      int a = adj_s[cur][row][w * 32 + lc];
      float wv = (a > 0) ? __expf(st[r]) : 0.f;   // |s|<=1: exp safe, no max needed
      dacc[r] += wv;
      int byo = row * 256 + (((w * 32 + lc) * 2) ^ ((row & 7) << 4));
      *(unsigned short*)(p_lds + byo) = (unsigned short)f2bf(wv);
    }
    __syncthreads();                   // barrier1: P visible

    // land adj(s+1)
    if (s < 15){
      *(i32x4*)&adj_s[nxt][arow][acold]      = av0;
      *(i32x4*)&adj_s[nxt][arow][acold + 4]  = av1;
      *(i32x4*)&adj_s[nxt][arow][acold + 8]  = av2;
      *(i32x4*)&adj_s[nxt][arow][acold + 12] = av3;
    }
    // ft B-frags second half (kk 4..7)
    bf16x8 bvB[8];
    #pragma unroll
    for (int kk = 0; kk < 4; ++kk){
      const unsigned short* fb = ftf + ((size_t)((j0 + 64 + kk * 16) >> 4) * 8 + w * 2) * 512 + (size_t)l * 8;
      bvB[kk * 2]     = ld16(fb);
      bvB[kk * 2 + 1] = ld16(fb + 512);
    }

    // PV: pv{0,1} += P[32i][128j] * ft[j][w*64 + {0,32} + 32d]
    #pragma unroll
    for (int kk = 0; kk < 8; ++kk){
      bf16x8 pa = ld16(p_lds + lc * 256 + ((kk * 32 + h * 16) ^ ((lc & 7) << 4)));
      bf16x8 b0 = (kk < 4) ? bvA[kk * 2]     : bvB[(kk - 4) * 2];
      bf16x8 b1 = (kk < 4) ? bvA[kk * 2 + 1] : bvB[(kk - 4) * 2 + 1];
      pv0 = __builtin_amdgcn_mfma_f32_32x32x16_bf16(pa, b0, pv0, 0, 0, 0);
      pv1 = __builtin_amdgcn_mfma_f32_32x32x16_bf16(pa, b1, pv1, 0, 0, 0);
    }
    __syncthreads();                   // barrier2: PV readers done
  }

  // den partials: reduce over this wave's 32 j-lanes; 16 partials (js*4 + w)
  #pragma unroll
  for (int r = 0; r < 16; ++r){
    float v = dacc[r];
    v += __shfl_xor(v, 1); v += __shfl_xor(v, 2); v += __shfl_xor(v, 4);
    v += __shfl_xor(v, 8); v += __shfl_xor(v, 16);
    if (lc == 0){
      int i = i0 + (r & 3) + 8 * (r >> 2) + 4 * h;
      den_p[(size_t)(js * 4 + w) * NN + i] = v;
    }
  }
  // num partials: coalesced stores (per-js region)
  float* np = num_p + (size_t)js * NN * DD;
  #pragma unroll
  for (int r = 0; r < 16; ++r){
    int i = i0 + (r & 3) + 8 * (r >> 2) + 4 * h;
    int d = w * 64 + lc;
    np[(size_t)i * DD + d]      = pv0[r];
    np[(size_t)i * DD + d + 32] = pv1[r];
  }
}

// ---------- finalize: sum 4 num / 16 den partials; blend ----------
__global__ __launch_bounds__(256) void k_final(const float* __restrict__ num_p,
                                               const float* __restrict__ den_p,
                                               const float* __restrict__ f,
                                               float* __restrict__ out){
  int gid = blockIdx.x * 256 + threadIdx.x;
  int i = gid >> 6;
  f32x4 nv = (f32x4){0.f,0.f,0.f,0.f};
  #pragma unroll
  for (int s = 0; s < 4; ++s)
    nv += *(const f32x4*)(num_p + (size_t)s * NN * DD + (size_t)gid * 4);
  float dv = 0.f;
  #pragma unroll
  for (int s = 0; s < 16; ++s)
    dv += den_p[(size_t)s * NN + i];
  f32x4 fv = *(const f32x4*)(f + (size_t)gid * 4);
  f32x4 o;
  if (dv > 0.f){
    float inv = 0.5f / dv;
    o = nv * inv + fv * 0.5f;
  } else {
    o = fv;   // no-neighbor row keeps features
  }
  *(f32x4*)(out + (size_t)gid * 4) = o;
}

extern "C" void kernel_launch(void* const* d_in, const int* in_sizes, int n_in,
                              void* d_out, int out_size, void* d_ws, size_t ws_size,
                              hipStream_t stream){
  (void)in_sizes; (void)n_in; (void)out_size;
  const float* feat = (const float*)d_in[0];
  const int*   adj  = (const int*)d_in[1];
  const float* Wq   = (const float*)d_in[2];
  const float* Wk   = (const float*)d_in[3];
  float* out = (float*)d_out;
  char* ws = (char*)d_ws;
  unsigned short* Qnf   = (unsigned short*)(ws);                 // 2MB frag-layout
  unsigned short* Kn    = (unsigned short*)(ws + (2u << 20));    // 2MB row-major
  unsigned short* ftf   = (unsigned short*)(ws + (4u << 20));    // 4MB frag-layout
  float*          num_p = (float*)(ws + (8u << 20));             // 4 x 8MB
  float*          den_p = (float*)(ws + (40u << 20));            // 16 x 32KB
  if (ws_size < (40u << 20) + (16u * NN * 4u)) return;           // ~40.5MB scratch

  k_prep<<<1024, 256, 0, stream>>>(feat, Wq, Wk, ftf, Qnf, Kn);
  k_attn<<<1024, 256, 0, stream>>>(adj, Qnf, Kn, ftf, num_p, den_p);
  k_final<<<2048, 256, 0, stream>>>(num_p, den_p, feat, out);
}